// Round 2
// baseline (801.560 us; speedup 1.0000x reference)
//
#include <hip/hip_runtime.h>

// Fused two-head classifier:
//   status = softmax(embs @ W_status^T + b_status)   (5)
//   flight = softmax(embs @ W_flight^T + b_flight)   (30)
//   out    = [s0, s2, s1, s4*flight, s3*flight]      (63)
//
// Round-2 design:
//  - embs staged through a 64 KB XOR-swizzled LDS tile (coalesced global
//    loads, conflict-free ds_read_b128 in row-per-lane pattern).
//  - lane owns 2 rows (R=2): 35 wave-uniform W s_loads feed 280 FMAs/iter.
//  - K split 4-way across the block's 4 waves; LDS reduction; wave 0 epilogue.
//  - 512 blocks x 256 threads = 2 blocks/CU, 8 waves/CU.

#define ROWS_PER_BLOCK 128
#define CHUNK_F4       32      // float4 per row per K-chunk (128 floats)
#define N_CHUNKS       8       // 1024 / 128
#define NOUT           35

__global__ __launch_bounds__(256, 2)
void fused_heads_kernel(const float* __restrict__ embs,
                        const float* __restrict__ W_status,
                        const float* __restrict__ b_status,
                        const float* __restrict__ W_flight,
                        const float* __restrict__ b_flight,
                        float* __restrict__ out) {
    // 64 KB shared: emb tile during the K loop, reduction buffer afterwards.
    __shared__ __align__(16) unsigned char smem[65536];
    float4* lds4 = (float4*)smem;                 // tile: [128 rows][32 f4], swizzled
    float4* red4 = (float4*)smem;                 // red:  [(3*128+r)*9 + j]

    const int tid  = threadIdx.x;
    const int lane = tid & 63;
    int part = __builtin_amdgcn_readfirstlane(tid >> 6);   // 0..3 = K-part

    const int row0 = blockIdx.x * ROWS_PER_BLOCK;

    const float4* E4  = (const float4*)embs;      // [rows][256]
    const float4* Ws4 = (const float4*)W_status;  // [5][256]
    const float4* Wf4 = (const float4*)W_flight;  // [30][256]

    float acc[2][NOUT];
#pragma unroll
    for (int r = 0; r < 2; ++r)
#pragma unroll
        for (int o = 0; o < NOUT; ++o) acc[r][o] = 0.0f;

    const int sr = tid >> 5;        // 0..7: row-within-pass for staging
    const int sc = tid & 31;        // 0..31: f4 col for staging

#pragma unroll 1
    for (int ch = 0; ch < N_CHUNKS; ++ch) {
        __syncthreads();   // previous chunk's compute reads finished

        // ---- stage 128 rows x 32 f4 (64 KB), coalesced, XOR-swizzled ----
#pragma unroll
        for (int p = 0; p < 16; ++p) {
            const int r = p * 8 + sr;
            const float4 v = E4[(size_t)(row0 + r) * 256 + ch * CHUNK_F4 + sc];
            lds4[r * 32 + (sc ^ (r & 7))] = v;
        }

        __syncthreads();   // tile visible

        // ---- compute: this wave covers f4 cols [part*8, part*8+8) ----
        const int swz = lane & 7;
#pragma unroll
        for (int i = 0; i < 8; ++i) {
            const int c4 = part * 8 + i;                 // uniform
            const int wc = ch * CHUNK_F4 + c4;           // uniform global f4 col

            const float4 v0 = lds4[lane * 32 + (c4 ^ swz)];
            const float4 v1 = lds4[(lane + 64) * 32 + (c4 ^ swz)];

#pragma unroll
            for (int o = 0; o < 5; ++o) {
                const float4 w = Ws4[o * 256 + wc];      // wave-uniform -> s_load
                float a0 = acc[0][o], a1 = acc[1][o];
                a0 = fmaf(v0.x, w.x, a0); a1 = fmaf(v1.x, w.x, a1);
                a0 = fmaf(v0.y, w.y, a0); a1 = fmaf(v1.y, w.y, a1);
                a0 = fmaf(v0.z, w.z, a0); a1 = fmaf(v1.z, w.z, a1);
                a0 = fmaf(v0.w, w.w, a0); a1 = fmaf(v1.w, w.w, a1);
                acc[0][o] = a0; acc[1][o] = a1;
            }
#pragma unroll
            for (int o = 0; o < 30; ++o) {
                const float4 w = Wf4[o * 256 + wc];      // wave-uniform -> s_load
                float a0 = acc[0][5 + o], a1 = acc[1][5 + o];
                a0 = fmaf(v0.x, w.x, a0); a1 = fmaf(v1.x, w.x, a1);
                a0 = fmaf(v0.y, w.y, a0); a1 = fmaf(v1.y, w.y, a1);
                a0 = fmaf(v0.z, w.z, a0); a1 = fmaf(v1.z, w.z, a1);
                a0 = fmaf(v0.w, w.w, a0); a1 = fmaf(v1.w, w.w, a1);
                acc[0][5 + o] = a0; acc[1][5 + o] = a1;
            }
        }
    }

    __syncthreads();   // all tile reads done before red overwrites it

    // ---- cross-part reduction: parts 1..3 dump partials to LDS ----
    if (part != 0) {
        float tmp[36];
#pragma unroll
        for (int rr = 0; rr < 2; ++rr) {
#pragma unroll
            for (int o = 0; o < NOUT; ++o) tmp[o] = acc[rr][o];
            tmp[35] = 0.0f;
            const int row = lane + rr * 64;
            const int base = ((part - 1) * 128 + row) * 9;
            const float4* t4 = (const float4*)tmp;
#pragma unroll
            for (int j = 0; j < 9; ++j) red4[base + j] = t4[j];
        }
    }
    __syncthreads();

    if (part == 0) {
#pragma unroll
        for (int rr = 0; rr < 2; ++rr) {
            const int row = lane + rr * 64;
            float v[36];
#pragma unroll
            for (int o = 0; o < NOUT; ++o) v[o] = acc[rr][o];
            v[35] = 0.0f;
#pragma unroll
            for (int p = 0; p < 3; ++p) {
                const int base = (p * 128 + row) * 9;
                float4* v4 = (float4*)v;
#pragma unroll
                for (int j = 0; j < 9; ++j) {
                    const float4 t = red4[base + j];
                    v4[j].x += t.x; v4[j].y += t.y; v4[j].z += t.z; v4[j].w += t.w;
                }
            }

            // ---- status softmax (5) ----
            float s[5];
#pragma unroll
            for (int j = 0; j < 5; ++j) s[j] = v[j] + b_status[j];
            float ms = s[0];
#pragma unroll
            for (int j = 1; j < 5; ++j) ms = fmaxf(ms, s[j]);
            float sums = 0.0f;
#pragma unroll
            for (int j = 0; j < 5; ++j) { s[j] = __expf(s[j] - ms); sums += s[j]; }
            const float invs = 1.0f / sums;

            // ---- flight softmax (30) ----
            float f[30];
#pragma unroll
            for (int j = 0; j < 30; ++j) f[j] = v[5 + j] + b_flight[j];
            float mf = f[0];
#pragma unroll
            for (int j = 1; j < 30; ++j) mf = fmaxf(mf, f[j]);
            float sumf = 0.0f;
#pragma unroll
            for (int j = 0; j < 30; ++j) { f[j] = __expf(f[j] - mf); sumf += f[j]; }
            const float invf = 1.0f / sumf;

            // ---- write 63 outputs ----
            float* orow = out + (size_t)(row0 + row) * 63;
            orow[0] = s[0] * invs;                    // no_flight  (status 0)
            orow[1] = s[2] * invs;                    // cancel     (status 2)
            orow[2] = s[1] * invs;                    // no_reservation (status 1)
            const float book   = s[4] * invs * invf;  // status 4
            const float change = s[3] * invs * invf;  // status 3
#pragma unroll
            for (int j = 0; j < 30; ++j) {
                orow[3 + j]  = book   * f[j];
                orow[33 + j] = change * f[j];
            }
        }
    }
}

extern "C" void kernel_launch(void* const* d_in, const int* in_sizes, int n_in,
                              void* d_out, int out_size, void* d_ws, size_t ws_size,
                              hipStream_t stream) {
    const float* embs     = (const float*)d_in[0];
    const float* W_status = (const float*)d_in[1];
    const float* b_status = (const float*)d_in[2];
    const float* W_flight = (const float*)d_in[3];
    const float* b_flight = (const float*)d_in[4];
    float* out = (float*)d_out;

    const int rows = in_sizes[0] / 1024;              // 65536
    const int grid = rows / ROWS_PER_BLOCK;           // 512

    fused_heads_kernel<<<grid, 256, 0, stream>>>(
        embs, W_status, b_status, W_flight, b_flight, out);
}

// Round 3
// 390.804 us; speedup vs baseline: 2.0511x; 2.0511x over previous
//
#include <hip/hip_runtime.h>
#include <math.h>

// Fused two-head classifier via bf16 MFMA GEMM:
//   C[65536 x 48] = embs[65536 x 1024] (bf16-cast) x B[1024 x 48]
//   B cols 0..4 = W_status, 5..34 = W_flight, 35..47 = zero pad.
//   Epilogue: dual softmax + gating, done with 16-lane shuffle butterflies
//   (C/D layout: col = lane&15, row = (lane>>4)*4 + reg).
//
// Per wave: 16 rows, full K=1024 (32 k-steps x 3 mfma_f32_16x16x32_bf16).
// A fragments loaded straight from global (lane = row n=lane&15,
// k-chunk (lane>>4)*8) with next-step prefetch; each row's 128B line region
// is fully consumed per k-step -> embs read exactly once (268 MB).
// B staged per K-half into 48 KB LDS in fragment order -> stride-1
// ds_read_b128, no scalar loads in the hot loop (avoids the lgkmcnt
// s_load/ds_read serialization that killed rounds 1-2).

typedef __bf16 bf16x8 __attribute__((ext_vector_type(8)));
typedef float  f32x4  __attribute__((ext_vector_type(4)));

#define ROWS_PER_BLOCK 256   // 16 waves * 16 rows
#define KSTEPS   32          // 1024 / 32
#define HALF_KS  16

__global__ __launch_bounds__(1024, 4)
void fused_heads_kernel(const float* __restrict__ embs,
                        const float* __restrict__ W_status,
                        const float* __restrict__ b_status,
                        const float* __restrict__ W_flight,
                        const float* __restrict__ b_flight,
                        float* __restrict__ out) {
    // B half-tile: [16 ks][3 frag][64 lanes] x 16B = 48 KB
    __shared__ bf16x8 Bsh[HALF_KS * 3 * 64];

    const int tid  = threadIdx.x;
    const int lane = tid & 63;
    const int wv   = tid >> 6;          // 0..15
    const int n    = lane & 15;         // MFMA row (A) / col (C)
    const int q    = lane >> 4;         // quad group 0..3

    const int rowbase = blockIdx.x * ROWS_PER_BLOCK + wv * 16;
    const float* aptr = embs + (size_t)(rowbase + n) * 1024 + q * 8;

    f32x4 acc0 = {0.f, 0.f, 0.f, 0.f};
    f32x4 acc1 = {0.f, 0.f, 0.f, 0.f};
    f32x4 acc2 = {0.f, 0.f, 0.f, 0.f};

    // prefetch A for k-step 0
    float4 ca0 = *(const float4*)(aptr);
    float4 ca1 = *(const float4*)(aptr + 4);

    for (int half = 0; half < 2; ++half) {
        __syncthreads();   // previous half's Bsh reads finished

        // ---- stage B half (3072 frags, 3 per thread), coalesced LDS writes ----
#pragma unroll
        for (int i = 0; i < 3; ++i) {
            const int d   = tid + i * 1024;
            const int L   = d & 63;
            const int ksf = d >> 6;                    // 0..47 = ksl*3 + f
            const int ksl = ksf / 3;
            const int f   = ksf - ksl * 3;
            const int bn  = f * 16 + (L & 15);         // B column 0..47
            const int bk  = (half * HALF_KS + ksl) * 32 + (L >> 4) * 8;
            bf16x8 w;
#pragma unroll
            for (int j = 0; j < 8; ++j) w[j] = (__bf16)0.0f;
            if (bn < 35) {
                const float* src = (bn < 5) ? (W_status + bn * 1024 + bk)
                                            : (W_flight + (bn - 5) * 1024 + bk);
                const float4 w0 = *(const float4*)(src);
                const float4 w1 = *(const float4*)(src + 4);
                w[0] = (__bf16)w0.x; w[1] = (__bf16)w0.y;
                w[2] = (__bf16)w0.z; w[3] = (__bf16)w0.w;
                w[4] = (__bf16)w1.x; w[5] = (__bf16)w1.y;
                w[6] = (__bf16)w1.z; w[7] = (__bf16)w1.w;
            }
            Bsh[d] = w;
        }
        __syncthreads();   // Bsh half visible

        // ---- 16 K-steps: prefetch A(ks+1), cvt, 3x ds_read_b128, 3x MFMA ----
#pragma unroll 4
        for (int kl = 0; kl < HALF_KS; ++kl) {
            const int ks  = half * HALF_KS + kl;
            const int nks = (ks < KSTEPS - 1) ? ks + 1 : ks;   // clamp, no OOB
            const float4 na0 = *(const float4*)(aptr + nks * 32);
            const float4 na1 = *(const float4*)(aptr + nks * 32 + 4);

            bf16x8 af;
            af[0] = (__bf16)ca0.x; af[1] = (__bf16)ca0.y;
            af[2] = (__bf16)ca0.z; af[3] = (__bf16)ca0.w;
            af[4] = (__bf16)ca1.x; af[5] = (__bf16)ca1.y;
            af[6] = (__bf16)ca1.z; af[7] = (__bf16)ca1.w;

            const bf16x8 b0 = Bsh[(kl * 3 + 0) * 64 + lane];
            const bf16x8 b1 = Bsh[(kl * 3 + 1) * 64 + lane];
            const bf16x8 b2 = Bsh[(kl * 3 + 2) * 64 + lane];

            acc0 = __builtin_amdgcn_mfma_f32_16x16x32_bf16(af, b0, acc0, 0, 0, 0);
            acc1 = __builtin_amdgcn_mfma_f32_16x16x32_bf16(af, b1, acc1, 0, 0, 0);
            acc2 = __builtin_amdgcn_mfma_f32_16x16x32_bf16(af, b2, acc2, 0, 0, 0);

            ca0 = na0; ca1 = na1;
        }
    }

    // ---- epilogue: per-row dual softmax across the 16-lane group ----
    // lane holds cols n, 16+n, 32+n for rows q*4+i (i = 0..3).
    const float bias0 = (n < 5) ? b_status[n] : b_flight[n - 5];
    const float bias1 = b_flight[n + 11];
    const float bias2 = (n < 3) ? b_flight[n + 27] : 0.0f;
    const int   gb    = lane & 48;   // group base lane

#pragma unroll
    for (int i = 0; i < 4; ++i) {
        const float v0 = acc0[i] + bias0;                       // col n
        const float v1 = acc1[i] + bias1;                       // col 16+n
        const float v2 = (n < 3) ? (acc2[i] + bias2) : -INFINITY; // col 32+n

        float ms = (n < 5) ? v0 : -INFINITY;                    // status max
        float mf = fmaxf((n >= 5) ? v0 : -INFINITY, fmaxf(v1, v2)); // flight max
#pragma unroll
        for (int m = 1; m < 16; m <<= 1) {
            ms = fmaxf(ms, __shfl_xor(ms, m));
            mf = fmaxf(mf, __shfl_xor(mf, m));
        }

        const float es  = (n < 5)  ? __expf(v0 - ms) : 0.0f;
        const float ef0 = (n >= 5) ? __expf(v0 - mf) : 0.0f;
        const float ef1 = __expf(v1 - mf);
        const float ef2 = (n < 3)  ? __expf(v2 - mf) : 0.0f;

        float ss = es;
        float sf = ef0 + ef1 + ef2;
#pragma unroll
        for (int m = 1; m < 16; m <<= 1) {
            ss += __shfl_xor(ss, m);
            sf += __shfl_xor(sf, m);
        }
        const float invs = 1.0f / ss;
        const float invf = 1.0f / sf;

        const float book   = __shfl(es, gb + 4) * invs * invf;  // s4 * invs * invf
        const float change = __shfl(es, gb + 3) * invs * invf;  // s3 * invs * invf

        float* orow = out + (size_t)(rowbase + q * 4 + i) * 63;
        if (n == 0) orow[0] = es * invs;            // no_flight  (status 0)
        if (n == 2) orow[1] = es * invs;            // cancel     (status 2)
        if (n == 1) orow[2] = es * invs;            // no_reservation (status 1)
        if (n >= 5) {                               // flight j = n-5  (cols 5..15)
            orow[3 + (n - 5)]  = book   * ef0;
            orow[33 + (n - 5)] = change * ef0;
        }
        orow[3 + (n + 11)]  = book   * ef1;         // flight j = n+11 (cols 16..31)
        orow[33 + (n + 11)] = change * ef1;
        if (n < 3) {                                // flight j = n+27 (cols 32..34)
            orow[3 + (n + 27)]  = book   * ef2;
            orow[33 + (n + 27)] = change * ef2;
        }
    }
}

extern "C" void kernel_launch(void* const* d_in, const int* in_sizes, int n_in,
                              void* d_out, int out_size, void* d_ws, size_t ws_size,
                              hipStream_t stream) {
    const float* embs     = (const float*)d_in[0];
    const float* W_status = (const float*)d_in[1];
    const float* b_status = (const float*)d_in[2];
    const float* W_flight = (const float*)d_in[3];
    const float* b_flight = (const float*)d_in[4];
    float* out = (float*)d_out;

    const int rows = in_sizes[0] / 1024;              // 65536
    const int grid = rows / ROWS_PER_BLOCK;           // 256

    fused_heads_kernel<<<grid, 1024, 0, stream>>>(
        embs, W_status, b_status, W_flight, b_flight, out);
}